// Round 12
// baseline (2835.394 us; speedup 1.0000x reference)
//
#include <hip/hip_runtime.h>

#define BB 64
#define TT 512
#define HH 1024
#define OUTN 32000
#define NDOM 4              // 4 independent domains: 16 batch rows each
#define NCB 32              // col-blocks per domain (32 cols each)
#define NWG (NDOM * NCB)    // 128 workgroups
#define NTH 128             // 2 waves; wave wv owns 16 of the WG's 32 cols
#define SLOT (BB * HH * 2)  // 128 KB per ring slot
#define FLAGS_BYTES 4096
#define HBUF_OFF FLAGS_BYTES
#define EMB_OFF (512 * 1024)
#define EMB_BYTES ((size_t)TT * BB * HH * 4)
// ws: [flags 4KB][ring of 3 slots x 128KB] ... [emb slab at 512KB]
// slot: [dom4][kb32][row16][col32] bf16; chunk = 16B = (row, 8 cols), one
// lane's dwordx4 (atomic unit); bit14 of chunk's first u16 = step phase
// (tanh => bit14==0 in data). slots0,1 = 0x00, slot2 = 0x40 init (R5 scheme).
// flags[dom*64 + cb*2 + wv]: monotonic, bumped by fire-and-forget
// global_atomic_add (executes AT the MALL -> poll line stays resident).

typedef __attribute__((ext_vector_type(8))) short s16x8;
typedef __attribute__((ext_vector_type(4))) float f32x4;
typedef __attribute__((ext_vector_type(4))) int i32x4;

static __device__ __forceinline__ unsigned short f2bf(float f) {
  union { float f; unsigned u; } a; a.f = f;
  unsigned r = a.u + 0x7fffu + ((a.u >> 16) & 1u);   // RNE
  return (unsigned short)(r >> 16);
}

static __device__ __forceinline__ float ftanh(float x) {
  float e = __expf(2.0f * x);
  return 1.0f - 2.0f * __builtin_amdgcn_rcpf(e + 1.0f);
}

#define ALD(idx, off_lit, vov)                                            \
  asm volatile("global_load_dwordx4 %0, %1, %2 offset:" #off_lit " sc1"   \
               : "=v"(areg[idx]) : "v"(vov), "s"(hprev) : "memory")

// all 32 A-chunk loads, areg[kb] <-> kb, exact vmcnt accounting
#define ISSUEA                                                             \
  ALD(0,0,vo0);  ALD(1,1024,vo0);  ALD(2,2048,vo0);  ALD(3,3072,vo0);      \
  ALD(4,0,vo1);  ALD(5,1024,vo1);  ALD(6,2048,vo1);  ALD(7,3072,vo1);      \
  ALD(8,0,vo2);  ALD(9,1024,vo2);  ALD(10,2048,vo2); ALD(11,3072,vo2);     \
  ALD(12,0,vo3); ALD(13,1024,vo3); ALD(14,2048,vo3); ALD(15,3072,vo3);     \
  ALD(16,0,vo4); ALD(17,1024,vo4); ALD(18,2048,vo4); ALD(19,3072,vo4);     \
  ALD(20,0,vo5); ALD(21,1024,vo5); ALD(22,2048,vo5); ALD(23,3072,vo5);     \
  ALD(24,0,vo6); ALD(25,1024,vo6); ALD(26,2048,vo6); ALD(27,3072,vo6);     \
  ALD(28,0,vo7); ALD(29,1024,vo7); ALD(30,2048,vo7); ALD(31,3072,vo7);

#define WAITV(n)                                                           \
  do { asm volatile("s_waitcnt vmcnt(" #n ")" ::: "memory");               \
       __builtin_amdgcn_sched_barrier(0); } while (0)

// verify phase bit + clear, group of 8 kb-blocks (16B store atomicity =>
// checking u16[0] of each chunk suffices)
#define CLRG(g)                                                            \
  { _Pragma("unroll") for (int j = 0; j < 8; ++j) {                        \
      unsigned u0 = (unsigned)areg[(g) * 8 + j][0];                        \
      bad |= (u0 ^ want) & 0x4000u;                                        \
      areg[(g) * 8 + j][0] = (int)(u0 & ~0x4000u); } }

// MFMA one group of 8 kb-blocks, fixed order, 4 independent chains
#define MFG(g)                                                             \
  { _Pragma("unroll") for (int j = 0; j < 8; ++j) {                        \
      union { i32x4 i; s16x8 s; } a_; a_.i = areg[(g) * 8 + j];            \
      s16x8 b_ = *reinterpret_cast<const s16x8*>(                          \
          &wlds[((((g) * 8 + j) * 2 + wv) * 64 + l) * 8]);                 \
      ac[j & 3] = __builtin_amdgcn_mfma_f32_16x16x32_bf16(                 \
          a_.s, b_, ac[j & 3], 0, 0, 0); } }

// emb[t][b][h] = Wxh[x[b][t]][h] (f32) — streaming pre-gather (R9-proven)
__global__ __launch_bounds__(256) void emb_gather(
    const int* __restrict__ x, const float* __restrict__ Wxh,
    float* __restrict__ emb) {
  int t = blockIdx.x >> 3;
  int b0 = (blockIdx.x & 7) * 8;
  int wv = threadIdx.x >> 6, l = threadIdx.x & 63;
  #pragma unroll
  for (int rr = 0; rr < 2; ++rr) {
    int b = b0 + wv * 2 + rr;
    int tok = x[b * TT + t];
    const float4* src = (const float4*)(Wxh + (size_t)tok * HH);
    float4* dst = (float4*)(emb + ((size_t)t * BB + b) * HH);
    #pragma unroll
    for (int c = 0; c < 4; ++c) dst[c * 64 + l] = src[c * 64 + l];
  }
}

__global__ __launch_bounds__(NTH, 1) void rnn_persist(
    const int* __restrict__ x, const float* __restrict__ Wxh,
    const float* __restrict__ Whh_w, const float* __restrict__ Whh_b,
    unsigned* __restrict__ flags, char* __restrict__ hbuf,
    const float* __restrict__ embp, int use_emb) {
  const int g = blockIdx.x;
  const int dom = g >> 5;          // batch rows [16*dom, +16)
  const int cb = g & 31;           // cols [32*cb, +32)
  const int tid = threadIdx.x;
  const int wv = tid >> 6;
  const int l = tid & 63;
  const int lr = l & 15;
  const int lq = l >> 4;

  __shared__ __align__(16) unsigned short wlds[32 * 2 * 64 * 8];  // 64 KB B-frags
  __shared__ __align__(16) unsigned short epi[2 * 256];           // wave-private

  // One-time B pack (MFMA B-fragment order)
  for (int e = tid; e < 32 * 2 * 64; e += NTH) {
    int kb = e >> 7;
    int nt = (e >> 6) & 1;
    int ln = e & 63;
    int col = cb * 32 + nt * 16 + (ln & 15);
    int k0 = kb * 32 + (ln >> 4) * 8;
    const float* src = Whh_w + (size_t)col * HH + k0;
    union { unsigned short u[8]; i32x4 v; } pk;
    #pragma unroll
    for (int j = 0; j < 8; ++j) pk.u[j] = f2bf(src[j]);
    *reinterpret_cast<i32x4*>(&wlds[(size_t)e * 8]) = pk.v;
  }
  const int mycol = cb * 32 + wv * 16 + lr;
  const float bias = Whh_b[mycol];
  __syncthreads();   // only barrier in the kernel

  int xrow[4], xv[4];
  #pragma unroll
  for (int i = 0; i < 4; ++i) {
    xrow[i] = (dom * 16 + lq * 4 + i) * TT;
    xv[i] = x[xrow[i]];
  }

  unsigned* flagsD = flags + dom * 64;
  const unsigned vo0 = (unsigned)(lr * 64 + lq * 16);
  const unsigned vo1 = vo0 + 4096, vo2 = vo0 + 8192, vo3 = vo0 + 12288;
  const unsigned vo4 = vo0 + 16384, vo5 = vo0 + 20480, vo6 = vo0 + 24576,
                 vo7 = vo0 + 28672;

  for (int s = 0; s < TT; ++s) {
    const char* hprev = hbuf + (s % 3) * SLOT + dom * 32768;
    char* hcur = hbuf + ((s + 1) % 3) * SLOT + dom * 32768;
    const unsigned want = ((unsigned)(s & 1)) << 14;

    // 1. poll: 64 wave-flags (256 B, MALL-resident via atomics) >= s
    if (s > 0) {
      const unsigned* fp = flagsD + l;
      int guard = 0;
      unsigned fv;
      do {
        asm volatile("global_load_dword %0, %1, off sc1\n\t"
                     "s_waitcnt vmcnt(0)"
                     : "=v"(fv) : "v"(fp) : "memory");
        if (++guard > (1 << 17)) break;   // safety valve
      } while (!__all(fv >= (unsigned)s));
      __builtin_amdgcn_sched_barrier(0);
    }

    // 2. A-loads (32 x 16B), then emb loads (drain under MFMA)
    i32x4 areg[32];
    ISSUEA;
    float evu[4];
    if (use_emb) {
      #pragma unroll
      for (int i = 0; i < 4; ++i)
        evu[i] = embp[((size_t)s * BB + dom * 16 + lq * 4 + i) * HH + mycol];
    } else {
      #pragma unroll
      for (int i = 0; i < 4; ++i) evu[i] = Wxh[(size_t)xv[i] * HH + mycol];
      int snext = (s + 1 < TT) ? (s + 1) : s;
      #pragma unroll
      for (int i = 0; i < 4; ++i) xv[i] = x[xrow[i] + snext];
    }

    // 3. wait A (4 emb/x-ish loads may trail), verify, MFMA
    unsigned bad = 0;
    if (use_emb) { WAITV(4); } else { WAITV(8); }
    CLRG(0); CLRG(1); CLRG(2); CLRG(3);
    if (!__all(bad == 0)) {
      // rare: flag overtook data in the fabric — poll again + reload
      int gr = 0;
      for (;;) {
        bad = 0;
        ISSUEA;
        asm volatile("s_waitcnt vmcnt(0)" ::: "memory");
        __builtin_amdgcn_sched_barrier(0);
        CLRG(0); CLRG(1); CLRG(2); CLRG(3);
        if (__all(bad == 0)) break;
        if (++gr > (1 << 15)) break;      // never hard-wedge
      }
    }
    f32x4 ac[4];
    #pragma unroll
    for (int c = 0; c < 4; ++c) ac[c] = (f32x4){0.f, 0.f, 0.f, 0.f};
    MFG(0); MFG(1); MFG(2); MFG(3);
    f32x4 acc = (ac[0] + ac[1]) + (ac[2] + ac[3]);
    WAITV(0);   // emb landed (hidden under verify+MFMA)

    // 4. epilogue, wave-private (C/D col=lane&15, row=(lane>>4)*4+i)
    #pragma unroll
    for (int i = 0; i < 4; ++i) {
      float v = ftanh(acc[i] + evu[i] + bias);
      epi[wv * 256 + (lq * 4 + i) * 16 + lr] = f2bf(v);
    }
    asm volatile("s_waitcnt lgkmcnt(0)" ::: "memory");
    __builtin_amdgcn_sched_barrier(0);

    // 5. wave stores its 32 chunks (16 rows x its 16 cols), phase-tagged,
    //    then bumps its own flag via fire-and-forget atomic (MALL-resident).
    {
      const unsigned tb0 = ((unsigned)((s + 1) & 1)) << 14;
      if (l < 32) {
        int r = l >> 1, cg = l & 1;
        i32x4 v = *reinterpret_cast<const i32x4*>(&epi[wv * 256 + r * 16 + cg * 8]);
        v[0] |= (int)tb0;
        char* dst = hcur + cb * 1024 + r * 64 + wv * 32 + cg * 16;
        asm volatile("global_store_dwordx4 %0, %1, off sc1"
                     :: "v"(dst), "v"(v) : "memory");
      }
      if (l == 0) {
        unsigned* fp = flagsD + cb * 2 + wv;
        unsigned one = 1u;
        asm volatile("global_atomic_add %0, %1, off"
                     :: "v"(fp), "v"(one) : "memory");
      }
    }
  }
}

// out[64][32000] = h_final @ Why^T + Why_b; h_512 = slot 2 (512%3==2),
// phase (512&1)==0 -> clean. Why tile staged in LDS ONCE per WG (shared by
// all 4 waves -> 4x less global traffic than per-wave conversion).
__global__ __launch_bounds__(256) void rnn_proj(
    const char* __restrict__ hfin, const float* __restrict__ Why_w,
    const float* __restrict__ Why_b, float* __restrict__ out) {
  const int tid = threadIdx.x;
  const int w = tid >> 6;          // wave w -> batch rows [16w, 16w+16)
  const int l = tid & 63;
  const int lr = l & 15;
  const int lq = l >> 4;
  const int nbase = blockIdx.x * 128;

  __shared__ __align__(16) unsigned short blds[8 * 64 * 8];  // 8 KB B-frags

  f32x4 acc[8];
  #pragma unroll
  for (int nt = 0; nt < 8; ++nt) acc[nt] = (f32x4){0.f, 0.f, 0.f, 0.f};

  const char* abase = hfin + (size_t)w * 32768 + lr * 64 + lq * 16;
  for (int kb = 0; kb < 32; ++kb) {
    // stage B fragments for this kb: 512 slots, 2 per thread
    #pragma unroll
    for (int h = 0; h < 2; ++h) {
      int e = tid + h * 256;
      int nt = e >> 6, ln = e & 63;
      int n = nbase + nt * 16 + (ln & 15);
      int k0 = kb * 32 + (ln >> 4) * 8;
      const float4* wp = (const float4*)(Why_w + (size_t)n * HH + k0);
      float4 w0 = wp[0];
      float4 w1 = wp[1];
      union { unsigned short u[8]; i32x4 v; } bb;
      bb.u[0] = f2bf(w0.x); bb.u[1] = f2bf(w0.y);
      bb.u[2] = f2bf(w0.z); bb.u[3] = f2bf(w0.w);
      bb.u[4] = f2bf(w1.x); bb.u[5] = f2bf(w1.y);
      bb.u[6] = f2bf(w1.z); bb.u[7] = f2bf(w1.w);
      *reinterpret_cast<i32x4*>(&blds[(size_t)e * 8]) = bb.v;
    }
    __syncthreads();
    s16x8 a = *reinterpret_cast<const s16x8*>(abase + kb * 1024);
    #pragma unroll
    for (int nt = 0; nt < 8; ++nt) {
      s16x8 b = *reinterpret_cast<const s16x8*>(&blds[(nt * 64 + l) * 8]);
      acc[nt] = __builtin_amdgcn_mfma_f32_16x16x32_bf16(a, b, acc[nt], 0, 0, 0);
    }
    __syncthreads();
  }
  #pragma unroll
  for (int nt = 0; nt < 8; ++nt) {
    int n = nbase + nt * 16 + lr;
    float bv = Why_b[n];
    #pragma unroll
    for (int i = 0; i < 4; ++i) {
      int b = w * 16 + lq * 4 + i;
      out[(size_t)b * OUTN + n] = acc[nt][i] + bv;
    }
  }
}

extern "C" void kernel_launch(void* const* d_in, const int* in_sizes, int n_in,
                              void* d_out, int out_size, void* d_ws, size_t ws_size,
                              hipStream_t stream) {
  const int* x = (const int*)d_in[0];
  const float* Wxh = (const float*)d_in[1];
  const float* Whh_w = (const float*)d_in[2];
  const float* Whh_b = (const float*)d_in[3];
  const float* Why_w = (const float*)d_in[4];
  const float* Why_b = (const float*)d_in[5];
  float* out = (float*)d_out;

  char* ws = (char*)d_ws;
  unsigned* flags = (unsigned*)d_ws;
  char* hbuf = ws + HBUF_OFF;
  float* emb = (float*)(ws + EMB_OFF);
  int use_emb = (ws_size >= EMB_OFF + EMB_BYTES) ? 1 : 0;

  // flags=0; slot0 = h_0 = zeros (phase0 valid); slot1 = 0x00 (!=phase1);
  // slot2 = 0x40 (bit14=1 != phase0). Re-done every call — deterministic.
  hipMemsetAsync(ws, 0x00, HBUF_OFF + 2 * SLOT, stream);
  hipMemsetAsync(hbuf + 2 * SLOT, 0x40, SLOT, stream);
  if (use_emb) emb_gather<<<TT * 8, 256, 0, stream>>>(x, Wxh, emb);
  rnn_persist<<<NWG, NTH, 0, stream>>>(x, Wxh, Whh_w, Whh_b, flags, hbuf,
                                       emb, use_emb);
  rnn_proj<<<OUTN / 128, 256, 0, stream>>>(hbuf + 2 * SLOT, Why_w, Why_b, out);
}

// Round 13
// 1710.230 us; speedup vs baseline: 1.6579x; 1.6579x over previous
//
#include <hip/hip_runtime.h>

#define BB 64
#define TT 512
#define HH 1024
#define OUTN 32000
#define NDOM 4              // 4 independent domains: 16 batch rows each
#define NCB 32              // col-blocks per domain (32 cols each)
#define NWG (NDOM * NCB)    // 128 workgroups
#define NTH 128             // 2 waves; wave wv owns 16 of the WG's 32 cols
#define SLOT (BB * HH * 2)  // 128 KB per ring slot
#define FLAGS_BYTES 4096
#define HBUF_OFF FLAGS_BYTES
#define EMB_OFF (512 * 1024)
#define EMB_BYTES ((size_t)TT * BB * HH * 4)
// ws: [flags 4KB][ring of 3 slots x 128KB] ... [emb slab at 512KB]
// slot: [dom4][kb32][row16][col32] bf16; chunk = 16B = (row, 8 cols), one
// lane's dwordx4 (atomic unit); bit14 of chunk's first u16 = step phase
// (tanh => bit14==0 in data). slot0,1 init 0x00; slot2 init 0x40 (R5 scheme).
// flags[dom*32+cb]: monotonic counter, PLAIN sc1 store by the same wave that
// issued the data stores (program order) — R5's empirically-good ordering.

typedef __attribute__((ext_vector_type(8))) short s16x8;
typedef __attribute__((ext_vector_type(4))) float f32x4;
typedef __attribute__((ext_vector_type(4))) int i32x4;

static __device__ __forceinline__ unsigned short f2bf(float f) {
  union { float f; unsigned u; } a; a.f = f;
  unsigned r = a.u + 0x7fffu + ((a.u >> 16) & 1u);   // RNE
  return (unsigned short)(r >> 16);
}

static __device__ __forceinline__ float ftanh(float x) {
  float e = __expf(2.0f * x);
  return 1.0f - 2.0f * __builtin_amdgcn_rcpf(e + 1.0f);
}

#define ALD(idx, off_lit, vov)                                            \
  asm volatile("global_load_dwordx4 %0, %1, %2 offset:" #off_lit " sc1"   \
               : "=v"(areg[idx]) : "v"(vov), "s"(hprev) : "memory")

// all 32 A-chunk loads, areg[kb] <-> kb, exact vmcnt accounting
#define ISSUEA                                                             \
  ALD(0,0,vo0);  ALD(1,1024,vo0);  ALD(2,2048,vo0);  ALD(3,3072,vo0);      \
  ALD(4,0,vo1);  ALD(5,1024,vo1);  ALD(6,2048,vo1);  ALD(7,3072,vo1);      \
  ALD(8,0,vo2);  ALD(9,1024,vo2);  ALD(10,2048,vo2); ALD(11,3072,vo2);     \
  ALD(12,0,vo3); ALD(13,1024,vo3); ALD(14,2048,vo3); ALD(15,3072,vo3);     \
  ALD(16,0,vo4); ALD(17,1024,vo4); ALD(18,2048,vo4); ALD(19,3072,vo4);     \
  ALD(20,0,vo5); ALD(21,1024,vo5); ALD(22,2048,vo5); ALD(23,3072,vo5);     \
  ALD(24,0,vo6); ALD(25,1024,vo6); ALD(26,2048,vo6); ALD(27,3072,vo6);     \
  ALD(28,0,vo7); ALD(29,1024,vo7); ALD(30,2048,vo7); ALD(31,3072,vo7);

#define WAITV(n)                                                           \
  do { asm volatile("s_waitcnt vmcnt(" #n ")" ::: "memory");               \
       __builtin_amdgcn_sched_barrier(0); } while (0)

// verify phase bit + clear, group of 8 kb-blocks
#define CLRG(g)                                                            \
  { _Pragma("unroll") for (int j = 0; j < 8; ++j) {                        \
      unsigned u0 = (unsigned)areg[(g) * 8 + j][0];                        \
      bad |= (u0 ^ want) & 0x4000u;                                        \
      areg[(g) * 8 + j][0] = (int)(u0 & ~0x4000u); } }

// MFMA one group of 8 kb-blocks, fixed order, 4 independent chains
#define MFG(g)                                                             \
  { _Pragma("unroll") for (int j = 0; j < 8; ++j) {                        \
      union { i32x4 i; s16x8 s; } a_; a_.i = areg[(g) * 8 + j];            \
      s16x8 b_ = *reinterpret_cast<const s16x8*>(                          \
          &wlds[((((g) * 8 + j) * 2 + wv) * 64 + l) * 8]);                 \
      ac[j & 3] = __builtin_amdgcn_mfma_f32_16x16x32_bf16(                 \
          a_.s, b_, ac[j & 3], 0, 0, 0); } }

// emb[t][b][h] = Wxh[x[b][t]][h] (f32) — streaming pre-gather (R9-proven)
__global__ __launch_bounds__(256) void emb_gather(
    const int* __restrict__ x, const float* __restrict__ Wxh,
    float* __restrict__ emb) {
  int t = blockIdx.x >> 3;
  int b0 = (blockIdx.x & 7) * 8;
  int wv = threadIdx.x >> 6, l = threadIdx.x & 63;
  #pragma unroll
  for (int rr = 0; rr < 2; ++rr) {
    int b = b0 + wv * 2 + rr;
    int tok = x[b * TT + t];
    const float4* src = (const float4*)(Wxh + (size_t)tok * HH);
    float4* dst = (float4*)(emb + ((size_t)t * BB + b) * HH);
    #pragma unroll
    for (int c = 0; c < 4; ++c) dst[c * 64 + l] = src[c * 64 + l];
  }
}

__global__ __launch_bounds__(NTH, 1) void rnn_persist(
    const int* __restrict__ x, const float* __restrict__ Wxh,
    const float* __restrict__ Whh_w, const float* __restrict__ Whh_b,
    unsigned* __restrict__ flags, char* __restrict__ hbuf,
    const float* __restrict__ embp, int use_emb) {
  const int g = blockIdx.x;
  const int dom = g >> 5;          // batch rows [16*dom, +16)
  const int cb = g & 31;           // cols [32*cb, +32)
  const int tid = threadIdx.x;
  const int wv = tid >> 6;
  const int l = tid & 63;
  const int lr = l & 15;
  const int lq = l >> 4;

  __shared__ __align__(16) unsigned short wlds[32 * 2 * 64 * 8];  // 64 KB B-frags
  __shared__ __align__(16) unsigned short epi[16 * 32];           // 1 KB repack

  // One-time B pack (MFMA B-fragment order)
  for (int e = tid; e < 32 * 2 * 64; e += NTH) {
    int kb = e >> 7;
    int nt = (e >> 6) & 1;
    int ln = e & 63;
    int col = cb * 32 + nt * 16 + (ln & 15);
    int k0 = kb * 32 + (ln >> 4) * 8;
    const float* src = Whh_w + (size_t)col * HH + k0;
    union { unsigned short u[8]; i32x4 v; } pk;
    #pragma unroll
    for (int j = 0; j < 8; ++j) pk.u[j] = f2bf(src[j]);
    *reinterpret_cast<i32x4*>(&wlds[(size_t)e * 8]) = pk.v;
  }
  const int mycol = cb * 32 + wv * 16 + lr;
  const float bias = Whh_b[mycol];
  __syncthreads();

  int xrow[4], xv[4];
  #pragma unroll
  for (int i = 0; i < 4; ++i) {
    xrow[i] = (dom * 16 + lq * 4 + i) * TT;
    xv[i] = x[xrow[i]];
  }

  // emb register double-buffer: evc = emb[s] (consumed), evn = emb[s+1]
  float evc[4], evn[4];
  if (use_emb) {
    #pragma unroll
    for (int i = 0; i < 4; ++i)
      evc[i] = embp[((size_t)0 * BB + dom * 16 + lq * 4 + i) * HH + mycol];
  }

  const unsigned* flagsD = flags + dom * 32;
  const unsigned vo0 = (unsigned)(lr * 64 + lq * 16);
  const unsigned vo1 = vo0 + 4096, vo2 = vo0 + 8192, vo3 = vo0 + 12288;
  const unsigned vo4 = vo0 + 16384, vo5 = vo0 + 20480, vo6 = vo0 + 24576,
                 vo7 = vo0 + 28672;

  for (int s = 0; s < TT; ++s) {
    const char* hprev = hbuf + (s % 3) * SLOT + dom * 32768;
    char* hcur = hbuf + ((s + 1) % 3) * SLOT + dom * 32768;
    const unsigned want = ((unsigned)(s & 1)) << 14;

    if (!use_emb) {   // fallback path: gather now (hides under poll drain)
      #pragma unroll
      for (int i = 0; i < 4; ++i) evc[i] = Wxh[(size_t)xv[i] * HH + mycol];
    }

    // 1. cheap readiness poll: 32 flag dwords (128 B) per iteration
    if (s > 0) {
      const unsigned* fp = flagsD + (l & 31);
      int guard = 0;
      unsigned fv;
      do {
        asm volatile("global_load_dword %0, %1, off sc1\n\t"
                     "s_waitcnt vmcnt(0)"
                     : "=v"(fv) : "v"(fp) : "memory");
        if (++guard > (1 << 17)) break;   // safety valve
      } while (!__all(fv >= (unsigned)s));
      __builtin_amdgcn_sched_barrier(0);
    }

    // 2. one-shot A-load (32 x 16B) + emb[s+1] prefetch (4 trailing loads)
    i32x4 areg[32];
    ISSUEA;
    if (use_emb) {
      int snext = (s + 1 < TT) ? (s + 1) : s;
      #pragma unroll
      for (int i = 0; i < 4; ++i) {
        const float* ep =
            embp + ((size_t)snext * BB + dom * 16 + lq * 4 + i) * HH + mycol;
        asm volatile("global_load_dword %0, %1, off"
                     : "=v"(evn[i]) : "v"(ep) : "memory");
      }
      WAITV(4);        // all 32 A-loads done; emb trails under MFMA
    } else {
      int snext = (s + 1 < TT) ? (s + 1) : s;
      #pragma unroll
      for (int i = 0; i < 4; ++i) xv[i] = x[xrow[i] + snext];
      WAITV(0);
    }

    // 3. verify phase bits; rare failure -> full reload (drains emb too, ok)
    unsigned bad = 0;
    CLRG(0); CLRG(1); CLRG(2); CLRG(3);
    if (!__all(bad == 0)) {
      int gr = 0;
      for (;;) {
        bad = 0;
        ISSUEA;
        asm volatile("s_waitcnt vmcnt(0)" ::: "memory");
        __builtin_amdgcn_sched_barrier(0);
        CLRG(0); CLRG(1); CLRG(2); CLRG(3);
        if (__all(bad == 0)) break;
        if (++gr > (1 << 15)) break;      // never hard-wedge
      }
    }

    // 4. 32 MFMA, fixed order
    f32x4 ac[4];
    #pragma unroll
    for (int c = 0; c < 4; ++c) ac[c] = (f32x4){0.f, 0.f, 0.f, 0.f};
    MFG(0); MFG(1); MFG(2); MFG(3);
    f32x4 acc = (ac[0] + ac[1]) + (ac[2] + ac[3]);
    WAITV(0);   // emb[s+1] landed (hidden under verify+MFMA)

    // 5. epilogue: C/D col=lane&15, row=(lane>>4)*4+i -> LDS repack [row][col]
    #pragma unroll
    for (int i = 0; i < 4; ++i) {
      float v = ftanh(acc[i] + evc[i] + bias);
      epi[(lq * 4 + i) * 32 + wv * 16 + lr] = f2bf(v);
    }
    if (use_emb) {
      #pragma unroll
      for (int i = 0; i < 4; ++i) evc[i] = evn[i];
    }
    __syncthreads();

    // 6. wave0: one wave-wide 1KB block store (phase-tagged chunks), then
    //    the block flag — PLAIN store, same wave, program order (R5-proven).
    if (tid < 64) {
      i32x4 v = *reinterpret_cast<const i32x4*>(&epi[tid * 8]);
      v[0] |= (int)(((unsigned)((s + 1) & 1)) << 14);
      char* dst = hcur + cb * 1024 + tid * 16;
      asm volatile("global_store_dwordx4 %0, %1, off sc1"
                   :: "v"(dst), "v"(v) : "memory");
      if (tid == 0) {
        unsigned sv = (unsigned)(s + 1);
        asm volatile("global_store_dword %0, %1, off sc1"
                     :: "v"(flagsD + cb), "v"(sv) : "memory");
      }
    }
  }
}

// out[64][32000] = h_final @ Why^T + Why_b; h_512 = slot 2 (512%3==2),
// phase (512&1)==0 -> clean. Why tile staged in LDS once per WG per kb
// (shared by all 4 waves -> 4x less global traffic). R11-proven (~30 us).
__global__ __launch_bounds__(256) void rnn_proj(
    const char* __restrict__ hfin, const float* __restrict__ Why_w,
    const float* __restrict__ Why_b, float* __restrict__ out) {
  const int tid = threadIdx.x;
  const int w = tid >> 6;          // wave w -> batch rows [16w, 16w+16)
  const int l = tid & 63;
  const int lr = l & 15;
  const int lq = l >> 4;
  const int nbase = blockIdx.x * 128;

  __shared__ __align__(16) unsigned short blds[8 * 64 * 8];  // 8 KB B-frags

  f32x4 acc[8];
  #pragma unroll
  for (int nt = 0; nt < 8; ++nt) acc[nt] = (f32x4){0.f, 0.f, 0.f, 0.f};

  const char* abase = hfin + (size_t)w * 32768 + lr * 64 + lq * 16;
  for (int kb = 0; kb < 32; ++kb) {
    #pragma unroll
    for (int h = 0; h < 2; ++h) {
      int e = tid + h * 256;
      int nt = e >> 6, ln = e & 63;
      int n = nbase + nt * 16 + (ln & 15);
      int k0 = kb * 32 + (ln >> 4) * 8;
      const float4* wp = (const float4*)(Why_w + (size_t)n * HH + k0);
      float4 w0 = wp[0];
      float4 w1 = wp[1];
      union { unsigned short u[8]; i32x4 v; } bb;
      bb.u[0] = f2bf(w0.x); bb.u[1] = f2bf(w0.y);
      bb.u[2] = f2bf(w0.z); bb.u[3] = f2bf(w0.w);
      bb.u[4] = f2bf(w1.x); bb.u[5] = f2bf(w1.y);
      bb.u[6] = f2bf(w1.z); bb.u[7] = f2bf(w1.w);
      *reinterpret_cast<i32x4*>(&blds[(size_t)e * 8]) = bb.v;
    }
    __syncthreads();
    s16x8 a = *reinterpret_cast<const s16x8*>(abase + kb * 1024);
    #pragma unroll
    for (int nt = 0; nt < 8; ++nt) {
      s16x8 b = *reinterpret_cast<const s16x8*>(&blds[(nt * 64 + l) * 8]);
      acc[nt] = __builtin_amdgcn_mfma_f32_16x16x32_bf16(a, b, acc[nt], 0, 0, 0);
    }
    __syncthreads();
  }
  #pragma unroll
  for (int nt = 0; nt < 8; ++nt) {
    int n = nbase + nt * 16 + lr;
    float bv = Why_b[n];
    #pragma unroll
    for (int i = 0; i < 4; ++i) {
      int b = w * 16 + lq * 4 + i;
      out[(size_t)b * OUTN + n] = acc[nt][i] + bv;
    }
  }
}

extern "C" void kernel_launch(void* const* d_in, const int* in_sizes, int n_in,
                              void* d_out, int out_size, void* d_ws, size_t ws_size,
                              hipStream_t stream) {
  const int* x = (const int*)d_in[0];
  const float* Wxh = (const float*)d_in[1];
  const float* Whh_w = (const float*)d_in[2];
  const float* Whh_b = (const float*)d_in[3];
  const float* Why_w = (const float*)d_in[4];
  const float* Why_b = (const float*)d_in[5];
  float* out = (float*)d_out;

  char* ws = (char*)d_ws;
  unsigned* flags = (unsigned*)d_ws;
  char* hbuf = ws + HBUF_OFF;
  float* emb = (float*)(ws + EMB_OFF);
  int use_emb = (ws_size >= EMB_OFF + EMB_BYTES) ? 1 : 0;

  // flags=0; slot0 = h_0 = zeros (phase0 valid); slot1 = 0x00 (!=phase1);
  // slot2 = 0x40 (bit14=1 != phase0). Re-done every call — deterministic.
  hipMemsetAsync(ws, 0x00, HBUF_OFF + 2 * SLOT, stream);
  hipMemsetAsync(hbuf + 2 * SLOT, 0x40, SLOT, stream);
  if (use_emb) emb_gather<<<TT * 8, 256, 0, stream>>>(x, Wxh, emb);
  rnn_persist<<<NWG, NTH, 0, stream>>>(x, Wxh, Whh_w, Whh_b, flags, hbuf,
                                       emb, use_emb);
  rnn_proj<<<OUTN / 128, 256, 0, stream>>>(hbuf + 2 * SLOT, Why_w, Why_b, out);
}